// Round 1
// baseline (464.997 us; speedup 1.0000x reference)
//
#include <hip/hip_runtime.h>
#include <math.h>

#define B_TOT 16384
#define DD    256
#define UU    32
#define NBR   8
#define MH    512
#define RH    256
#define KIN   288
#define NY    20

typedef unsigned short u16;
typedef __attribute__((ext_vector_type(8))) short bfx8;
typedef __attribute__((ext_vector_type(4))) short bfx4;
typedef __attribute__((ext_vector_type(4))) float fx4;

#define MFMA(a, b, c) __builtin_amdgcn_mfma_f32_16x16x32_bf16((a), (b), (c), 0, 0, 0)

__device__ __forceinline__ u16 f2bf(float f) {
  union { float f; unsigned u; } v; v.f = f;
  unsigned r = v.u + 0x7FFFu + ((v.u >> 16) & 1u);   // RNE
  return (u16)(r >> 16);
}
__device__ __forceinline__ float bf2f(u16 u) {
  union { unsigned u; float f; } v; v.u = ((unsigned)u) << 16;
  return v.f;
}

// ---------------------------------------------------------------------------
// prep: fp32 -> bf16 weights, W_out transpose to [d][n*RH+r], sigmoid(gates)
// ---------------------------------------------------------------------------
__global__ void skolr_prep(const float* __restrict__ W1, const float* __restrict__ W2,
                           const float* __restrict__ rnnB, const float* __restrict__ Wout,
                           const float* __restrict__ gates,
                           u16* __restrict__ w1b, u16* __restrict__ w2b, u16* __restrict__ bb,
                           u16* __restrict__ wotb, float* __restrict__ sigg)
{
  int i = blockIdx.x * 256 + threadIdx.x;
  const int S0 = NBR * MH * DD;    // 1048576
  const int S1 = NBR * RH * MH;    // 1048576
  const int S2 = NBR * RH * KIN;   // 589824
  const int S3 = NBR * DD * RH;    // 524288
  const int S4 = NBR * DD;         // 2048
  if (i < S0) { w1b[i] = f2bf(W1[i]); return; }
  i -= S0;
  if (i < S1) { w2b[i] = f2bf(W2[i]); return; }
  i -= S1;
  if (i < S2) { bb[i] = f2bf(rnnB[i]); return; }
  i -= S2;
  if (i < S3) {
    int nn = i / (DD * RH);
    int rem = i - nn * DD * RH;
    int d = rem / RH;
    int r = rem - d * RH;
    wotb[(size_t)d * (NBR * RH) + nn * RH + r] = f2bf(Wout[i]);
    return;
  }
  i -= S3;
  if (i < S4) sigg[i] = 1.0f / (1.0f + expf(-gates[i]));
}

// ---------------------------------------------------------------------------
// fused stages 1-3: per (64-row batch tile, branch n):
//   xT = W1 @ zg^T ; LN(h) ; GELU ; gT = W2 @ x^T ; binT = rnnB @ [g,ut*dt]^T
// writes b_inp bf16 to bing[b][n*RH + r]
// LDS: smA = zg tile / g tile / LN stats (32KB); smB = LN partials / x half tile
//       / bin tile (32KB).  XOR-swizzled 16B chunks everywhere.
// ---------------------------------------------------------------------------
__global__ __launch_bounds__(512, 2)
void skolr_fused(const float* __restrict__ zt, const float* __restrict__ dtp,
                 const float* __restrict__ ut,
                 const u16* __restrict__ w1b, const float* __restrict__ b1,
                 const float* __restrict__ lng, const float* __restrict__ lnb,
                 const u16* __restrict__ w2b, const float* __restrict__ b2v,
                 const u16* __restrict__ rnnb, const float* __restrict__ sigg,
                 u16* __restrict__ bing)
{
  __shared__ __align__(16) char smA[32768];
  __shared__ __align__(16) char smB[32768];
  const int tid = threadIdx.x;
  const int w  = tid >> 6;
  const int l  = tid & 63;
  const int lr = l & 15;   // lane row-within-tile
  const int lg = l >> 4;   // k-group
  const int b0 = blockIdx.x * 64;
  const int n  = blockIdx.y;
  const float dtv = dtp[0];

  // ---- phase 0: stage zg = zt * sigmoid(gates[n]) as bf16 into smA (swizzled)
  #pragma unroll
  for (int j = 0; j < 4; ++j) {
    int q = tid + (j << 9);          // 0..2047 chunks (64 rows x 32 chunks)
    int row = q >> 5, c = q & 31;
    const float* zp = zt + (size_t)(b0 + row) * DD + c * 8;
    const float* sp = sigg + n * DD + c * 8;
    float4 z0 = *(const float4*)zp;
    float4 z1 = *(const float4*)(zp + 4);
    float4 s0 = *(const float4*)sp;
    float4 s1 = *(const float4*)(sp + 4);
    bfx8 v;
    v[0] = f2bf(z0.x * s0.x); v[1] = f2bf(z0.y * s0.y);
    v[2] = f2bf(z0.z * s0.z); v[3] = f2bf(z0.w * s0.w);
    v[4] = f2bf(z1.x * s1.x); v[5] = f2bf(z1.y * s1.y);
    v[6] = f2bf(z1.z * s1.z); v[7] = f2bf(z1.w * s1.w);
    *(bfx8*)(smA + row * 512 + ((c ^ (row & 7)) << 4)) = v;
  }
  // ut*dt B-fragments, kept in registers for stage 3 (k = 256..287)
  bfx8 ufrag[4];
  #pragma unroll
  for (int nt = 0; nt < 4; ++nt) {
    const float* up = ut + (size_t)(b0 + nt * 16 + lr) * UU + (lg << 3);
    float4 u0 = *(const float4*)up;
    float4 u1 = *(const float4*)(up + 4);
    bfx8 v;
    v[0] = f2bf(u0.x * dtv); v[1] = f2bf(u0.y * dtv);
    v[2] = f2bf(u0.z * dtv); v[3] = f2bf(u0.w * dtv);
    v[4] = f2bf(u1.x * dtv); v[5] = f2bf(u1.y * dtv);
    v[6] = f2bf(u1.z * dtv); v[7] = f2bf(u1.w * dtv);
    ufrag[nt] = v;
  }
  __syncthreads();   // (1)

  // ---- phase 1: xT[h][b] = W1[n] @ zg^T   M=512(h) N=64(b) K=256(d)
  const int h0 = w * 64;
  fx4 acc1[4][4];
  #pragma unroll
  for (int mt = 0; mt < 4; ++mt)
    #pragma unroll
    for (int nt = 0; nt < 4; ++nt)
      acc1[mt][nt] = (fx4){0.f, 0.f, 0.f, 0.f};
  {
    const u16* w1base = w1b + (size_t)n * MH * DD;
    #pragma unroll
    for (int kk = 0; kk < 8; ++kk) {
      bfx8 bfr[4];
      #pragma unroll
      for (int nt = 0; nt < 4; ++nt) {
        int b = nt * 16 + lr;
        bfr[nt] = *(const bfx8*)(smA + b * 512 + ((((kk << 2) + lg) ^ (b & 7)) << 4));
      }
      #pragma unroll
      for (int mt = 0; mt < 4; ++mt) {
        bfx8 af = *(const bfx8*)(w1base + (size_t)(h0 + mt * 16 + lr) * DD + (kk << 5) + (lg << 3));
        #pragma unroll
        for (int nt = 0; nt < 4; ++nt)
          acc1[mt][nt] = MFMA(af, bfr[nt], acc1[mt][nt]);
      }
    }
  }
  // + b1 (depends on h = row only)
  #pragma unroll
  for (int mt = 0; mt < 4; ++mt) {
    fx4 bv = *(const fx4*)(b1 + n * MH + h0 + mt * 16 + (lg << 2));
    #pragma unroll
    for (int nt = 0; nt < 4; ++nt)
      acc1[mt][nt] += bv;
  }

  // ---- phase 2: LayerNorm stats over h (per batch row b)
  {
    float* red = (float*)smB;   // [2][8][64]
    #pragma unroll
    for (int nt = 0; nt < 4; ++nt) {
      float s1 = 0.f, s2 = 0.f;
      #pragma unroll
      for (int mt = 0; mt < 4; ++mt)
        #pragma unroll
        for (int r = 0; r < 4; ++r) { float v = acc1[mt][nt][r]; s1 += v; s2 += v * v; }
      s1 += __shfl_xor(s1, 16); s1 += __shfl_xor(s1, 32);
      s2 += __shfl_xor(s2, 16); s2 += __shfl_xor(s2, 32);
      if (l < 16) { red[w * 64 + nt * 16 + l] = s1; red[512 + w * 64 + nt * 16 + l] = s2; }
    }
  }
  __syncthreads();   // (2)
  float* mstat = (float*)smA;   // aliases dead zg row 0; overwritten again by g-pack later
  if (tid < 64) {
    float* red = (float*)smB;
    float ms = 0.f, ss = 0.f;
    #pragma unroll
    for (int wv = 0; wv < 8; ++wv) { ms += red[wv * 64 + tid]; ss += red[512 + wv * 64 + tid]; }
    float mean = ms * (1.f / 512.f);
    float var  = ss * (1.f / 512.f) - mean * mean;
    mstat[tid]      = mean;
    mstat[64 + tid] = rsqrtf(var + 1e-5f);
  }
  __syncthreads();   // (3)

  // ---- phase 2.5: LN apply + exact GELU, in registers
  #pragma unroll
  for (int mt = 0; mt < 4; ++mt) {
    fx4 g4 = *(const fx4*)(lng + n * MH + h0 + mt * 16 + (lg << 2));
    fx4 e4 = *(const fx4*)(lnb + n * MH + h0 + mt * 16 + (lg << 2));
    #pragma unroll
    for (int nt = 0; nt < 4; ++nt) {
      int b = nt * 16 + lr;
      float mean = mstat[b], rstd = mstat[64 + b];
      #pragma unroll
      for (int r = 0; r < 4; ++r) {
        float v = (acc1[mt][nt][r] - mean) * rstd * g4[r] + e4[r];
        acc1[mt][nt][r] = 0.5f * v * (1.f + erff(v * 0.70710678118654752f));
      }
    }
  }

  // ---- phase 3a: waves 0..3 pack x half0 (h 0..255) -> smB [b][h'] swizzled
  if (w < 4) {
    #pragma unroll
    for (int mt = 0; mt < 4; ++mt)
      #pragma unroll
      for (int nt = 0; nt < 4; ++nt) {
        int b = nt * 16 + lr;
        bfx4 p;
        p[0] = f2bf(acc1[mt][nt][0]); p[1] = f2bf(acc1[mt][nt][1]);
        p[2] = f2bf(acc1[mt][nt][2]); p[3] = f2bf(acc1[mt][nt][3]);
        int bytecol = (h0 + mt * 16 + (lg << 2)) * 2;
        *(bfx4*)(smB + b * 512 + (((bytecol >> 4) ^ (b & 7)) << 4) + (bytecol & 15)) = p;
      }
  }
  __syncthreads();   // (4)

  // ---- phase 4a: gT[r][b] partial, K = h 0..255
  const int r0 = w * 32;
  fx4 acc2[2][4];
  #pragma unroll
  for (int mt = 0; mt < 2; ++mt)
    #pragma unroll
    for (int nt = 0; nt < 4; ++nt)
      acc2[mt][nt] = (fx4){0.f, 0.f, 0.f, 0.f};
  const u16* w2base = w2b + (size_t)n * RH * MH;
  #pragma unroll
  for (int kk = 0; kk < 8; ++kk) {
    bfx8 xb[4];
    #pragma unroll
    for (int nt = 0; nt < 4; ++nt) {
      int b = nt * 16 + lr;
      xb[nt] = *(const bfx8*)(smB + b * 512 + ((((kk << 2) + lg) ^ (b & 7)) << 4));
    }
    #pragma unroll
    for (int mt = 0; mt < 2; ++mt) {
      bfx8 af = *(const bfx8*)(w2base + (size_t)(r0 + mt * 16 + lr) * MH + (kk << 5) + (lg << 3));
      #pragma unroll
      for (int nt = 0; nt < 4; ++nt)
        acc2[mt][nt] = MFMA(af, xb[nt], acc2[mt][nt]);
    }
  }
  __syncthreads();   // (5)

  // ---- phase 3b: waves 4..7 pack x half1 (h 256..511)
  if (w >= 4) {
    #pragma unroll
    for (int mt = 0; mt < 4; ++mt)
      #pragma unroll
      for (int nt = 0; nt < 4; ++nt) {
        int b = nt * 16 + lr;
        bfx4 p;
        p[0] = f2bf(acc1[mt][nt][0]); p[1] = f2bf(acc1[mt][nt][1]);
        p[2] = f2bf(acc1[mt][nt][2]); p[3] = f2bf(acc1[mt][nt][3]);
        int bytecol = (h0 - 256 + mt * 16 + (lg << 2)) * 2;
        *(bfx4*)(smB + b * 512 + (((bytecol >> 4) ^ (b & 7)) << 4) + (bytecol & 15)) = p;
      }
  }
  __syncthreads();   // (6)

  // ---- phase 4b: K = h 256..511, then + b2, pack g -> smA
  #pragma unroll
  for (int kk = 8; kk < 16; ++kk) {
    bfx8 xb[4];
    #pragma unroll
    for (int nt = 0; nt < 4; ++nt) {
      int b = nt * 16 + lr;
      xb[nt] = *(const bfx8*)(smB + b * 512 + (((((kk - 8) << 2) + lg) ^ (b & 7)) << 4));
    }
    #pragma unroll
    for (int mt = 0; mt < 2; ++mt) {
      bfx8 af = *(const bfx8*)(w2base + (size_t)(r0 + mt * 16 + lr) * MH + (kk << 5) + (lg << 3));
      #pragma unroll
      for (int nt = 0; nt < 4; ++nt)
        acc2[mt][nt] = MFMA(af, xb[nt], acc2[mt][nt]);
    }
  }
  #pragma unroll
  for (int mt = 0; mt < 2; ++mt) {
    fx4 bz = *(const fx4*)(b2v + n * RH + r0 + mt * 16 + (lg << 2));
    #pragma unroll
    for (int nt = 0; nt < 4; ++nt)
      acc2[mt][nt] += bz;
  }
  #pragma unroll
  for (int mt = 0; mt < 2; ++mt)
    #pragma unroll
    for (int nt = 0; nt < 4; ++nt) {
      int b = nt * 16 + lr;
      bfx4 p;
      p[0] = f2bf(acc2[mt][nt][0]); p[1] = f2bf(acc2[mt][nt][1]);
      p[2] = f2bf(acc2[mt][nt][2]); p[3] = f2bf(acc2[mt][nt][3]);
      int bytecol = (r0 + mt * 16 + (lg << 2)) * 2;
      *(bfx4*)(smA + b * 512 + (((bytecol >> 4) ^ (b & 7)) << 4) + (bytecol & 15)) = p;
    }
  __syncthreads();   // (7)

  // ---- phase 5: binT[r][b] = rnnB @ [g, ut*dt]^T   K = 288
  fx4 acc3[2][4];
  #pragma unroll
  for (int mt = 0; mt < 2; ++mt)
    #pragma unroll
    for (int nt = 0; nt < 4; ++nt)
      acc3[mt][nt] = (fx4){0.f, 0.f, 0.f, 0.f};
  const u16* rbase = rnnb + (size_t)n * RH * KIN;
  #pragma unroll
  for (int kk = 0; kk < 8; ++kk) {
    bfx8 gb[4];
    #pragma unroll
    for (int nt = 0; nt < 4; ++nt) {
      int b = nt * 16 + lr;
      gb[nt] = *(const bfx8*)(smA + b * 512 + ((((kk << 2) + lg) ^ (b & 7)) << 4));
    }
    #pragma unroll
    for (int mt = 0; mt < 2; ++mt) {
      bfx8 af = *(const bfx8*)(rbase + (size_t)(r0 + mt * 16 + lr) * KIN + (kk << 5) + (lg << 3));
      #pragma unroll
      for (int nt = 0; nt < 4; ++nt)
        acc3[mt][nt] = MFMA(af, gb[nt], acc3[mt][nt]);
    }
  }
  // k = 256..287 : ut*dt from registers
  #pragma unroll
  for (int mt = 0; mt < 2; ++mt) {
    bfx8 af = *(const bfx8*)(rbase + (size_t)(r0 + mt * 16 + lr) * KIN + 256 + (lg << 3));
    #pragma unroll
    for (int nt = 0; nt < 4; ++nt)
      acc3[mt][nt] = MFMA(af, ufrag[nt], acc3[mt][nt]);
  }
  // pack bin -> smB
  #pragma unroll
  for (int mt = 0; mt < 2; ++mt)
    #pragma unroll
    for (int nt = 0; nt < 4; ++nt) {
      int b = nt * 16 + lr;
      bfx4 p;
      p[0] = f2bf(acc3[mt][nt][0]); p[1] = f2bf(acc3[mt][nt][1]);
      p[2] = f2bf(acc3[mt][nt][2]); p[3] = f2bf(acc3[mt][nt][3]);
      int bytecol = (r0 + mt * 16 + (lg << 2)) * 2;
      *(bfx4*)(smB + b * 512 + (((bytecol >> 4) ^ (b & 7)) << 4) + (bytecol & 15)) = p;
    }
  __syncthreads();   // (8)

  // ---- phase 6: smB -> bing[b][n*RH + r] (coalesced 128B segments)
  {
    int row = tid >> 3;
    int tc  = tid & 7;
    #pragma unroll
    for (int j = 0; j < 4; ++j) {
      int c = tc + (j << 3);
      int4 v = *(const int4*)(smB + row * 512 + ((c ^ (row & 7)) << 4));
      *(int4*)(bing + (size_t)(b0 + row) * (NBR * RH) + n * RH + c * 8) = v;
    }
  }
}

// ---------------------------------------------------------------------------
// final: zt1T[d][b] = WoT @ b_inp^T (K = 2048), store zt1 fp32,
//        then yt1 = zt1 @ C^T + (ut*dt) @ Dm^T from an LDS copy of zt1
// ---------------------------------------------------------------------------
__global__ __launch_bounds__(512, 2)
void skolr_final(const u16* __restrict__ bing, const u16* __restrict__ wotb,
                 const float* __restrict__ ut, const float* __restrict__ dtp,
                 const float* __restrict__ Cm, const float* __restrict__ Dm,
                 float* __restrict__ outp)
{
  __shared__ __align__(16) char sB[32768];
  __shared__ __align__(16) u16 sZ[64 * 256];
  const int tid = threadIdx.x;
  const int w  = tid >> 6;
  const int l  = tid & 63;
  const int lr = l & 15;
  const int lg = l >> 4;
  const int b0 = blockIdx.x * 64;
  const int d0 = w * 32;
  fx4 acc[2][4];
  #pragma unroll
  for (int mt = 0; mt < 2; ++mt)
    #pragma unroll
    for (int nt = 0; nt < 4; ++nt)
      acc[mt][nt] = (fx4){0.f, 0.f, 0.f, 0.f};

  for (int ks = 0; ks < 8; ++ks) {
    // stage 64 x 256 bf16 K-slice of b_inp (swizzled)
    #pragma unroll
    for (int j = 0; j < 4; ++j) {
      int q = tid + (j << 9);
      int row = q >> 5, c = q & 31;
      int4 v = *(const int4*)(bing + (size_t)(b0 + row) * 2048 + (ks << 8) + c * 8);
      *(int4*)(sB + row * 512 + ((c ^ (row & 7)) << 4)) = v;
    }
    __syncthreads();
    #pragma unroll
    for (int kk = 0; kk < 8; ++kk) {
      bfx8 bf[4];
      #pragma unroll
      for (int nt = 0; nt < 4; ++nt) {
        int b = nt * 16 + lr;
        bf[nt] = *(const bfx8*)(sB + b * 512 + ((((kk << 2) + lg) ^ (b & 7)) << 4));
      }
      #pragma unroll
      for (int mt = 0; mt < 2; ++mt) {
        bfx8 af = *(const bfx8*)(wotb + (size_t)(d0 + mt * 16 + lr) * 2048 + (ks << 8) + (kk << 5) + (lg << 3));
        #pragma unroll
        for (int nt = 0; nt < 4; ++nt)
          acc[mt][nt] = MFMA(af, bf[nt], acc[mt][nt]);
      }
    }
    __syncthreads();
  }

  // epilogue: zt1 -> global fp32 + LDS bf16 copy for yt1
  #pragma unroll
  for (int mt = 0; mt < 2; ++mt)
    #pragma unroll
    for (int nt = 0; nt < 4; ++nt) {
      int b = nt * 16 + lr;
      int d = d0 + mt * 16 + (lg << 2);
      *(fx4*)(outp + (size_t)(b0 + b) * DD + d) = acc[mt][nt];
      bfx4 p;
      p[0] = f2bf(acc[mt][nt][0]); p[1] = f2bf(acc[mt][nt][1]);
      p[2] = f2bf(acc[mt][nt][2]); p[3] = f2bf(acc[mt][nt][3]);
      int bytecol = d * 2;
      *(bfx4*)((char*)sZ + b * 512 + (((bytecol >> 4) ^ (b & 7)) << 4) + (bytecol & 15)) = p;
    }
  __syncthreads();

  const float dtv = dtp[0];
  for (int i = tid; i < 64 * NY; i += 512) {
    int b = i / NY;
    int y = i - b * NY;
    float sum = 0.f;
    #pragma unroll 4
    for (int dc = 0; dc < 32; ++dc) {
      bfx8 zv = *(const bfx8*)((const char*)sZ + b * 512 + ((dc ^ (b & 7)) << 4));
      const float* cp = Cm + y * DD + dc * 8;
      float4 c0 = *(const float4*)cp;
      float4 c1 = *(const float4*)(cp + 4);
      sum += bf2f(zv[0]) * c0.x + bf2f(zv[1]) * c0.y + bf2f(zv[2]) * c0.z + bf2f(zv[3]) * c0.w;
      sum += bf2f(zv[4]) * c1.x + bf2f(zv[5]) * c1.y + bf2f(zv[6]) * c1.z + bf2f(zv[7]) * c1.w;
    }
    const float* up = ut + (size_t)(b0 + b) * UU;
    const float* dp = Dm + y * UU;
    #pragma unroll
    for (int u = 0; u < 32; u += 4) {
      float4 uu = *(const float4*)(up + u);
      float4 dd = *(const float4*)(dp + u);
      sum += dtv * (uu.x * dd.x + uu.y * dd.y + uu.z * dd.z + uu.w * dd.w);
    }
    outp[(size_t)B_TOT * DD + (size_t)(b0 + b) * NY + y] = sum;
  }
}

// ---------------------------------------------------------------------------
extern "C" void kernel_launch(void* const* d_in, const int* in_sizes, int n_in,
                              void* d_out, int out_size, void* d_ws, size_t ws_size,
                              hipStream_t stream)
{
  (void)in_sizes; (void)n_in; (void)out_size; (void)ws_size;
  const float* zt    = (const float*)d_in[0];
  const float* dtp   = (const float*)d_in[1];
  const float* ut    = (const float*)d_in[2];
  const float* gates = (const float*)d_in[3];
  const float* W1    = (const float*)d_in[4];
  const float* b1    = (const float*)d_in[5];
  const float* lng   = (const float*)d_in[6];
  const float* lnb   = (const float*)d_in[7];
  const float* W2    = (const float*)d_in[8];
  const float* b2    = (const float*)d_in[9];
  // d_in[10] = lam_r, d_in[11] = lam_i : unused (h0 = 0 => lambda drops out)
  const float* rnnB  = (const float*)d_in[12];
  const float* Wout  = (const float*)d_in[13];
  const float* Cm    = (const float*)d_in[14];
  const float* Dm    = (const float*)d_in[15];
  float* outp = (float*)d_out;
  char* ws = (char*)d_ws;

  u16*   w1b  = (u16*)(ws + 0);            // 2,097,152 B
  u16*   w2b  = (u16*)(ws + 2097152);      // 2,097,152 B
  u16*   bb   = (u16*)(ws + 4194304);      // 1,179,648 B
  u16*   wotb = (u16*)(ws + 5373952);      // 1,048,576 B
  float* sigg = (float*)(ws + 6422528);    //     8,192 B
  u16*   bing = (u16*)(ws + 6430720);      // 67,108,864 B  (total ~70.1 MB)

  skolr_prep<<<12552, 256, 0, stream>>>(W1, W2, rnnB, Wout, gates, w1b, w2b, bb, wotb, sigg);
  skolr_fused<<<dim3(256, 8), 512, 0, stream>>>(zt, dtp, ut, w1b, b1, lng, lnb, w2b, b2, bb, sigg, bing);
  skolr_final<<<256, 512, 0, stream>>>(bing, wotb, ut, dtp, Cm, Dm, outp);
}